// Round 1
// baseline (413.235 us; speedup 1.0000x reference)
//
#include <hip/hip_runtime.h>
#include <stdint.h>

#define BATCH 16384
#define IN_F 2048
#define OUT_F 2048

typedef unsigned short u16;
typedef __attribute__((ext_vector_type(8))) short bf16x8;
typedef __attribute__((ext_vector_type(4))) float f32x4;

__device__ __forceinline__ u16 f2bf(float f) {
  union { float f; uint32_t u; } v; v.f = f;
  uint32_t u = v.u;
  u += 0x7FFFu + ((u >> 16) & 1u);   // round-to-nearest-even
  return (u16)(u >> 16);
}

// ---- prologue: fp32 -> bf16 conversion kernels ----

__global__ void cvt_x_kernel(const float4* __restrict__ x, u16* __restrict__ out) {
  int i = blockIdx.x * 256 + threadIdx.x;
  float4 v = x[i];
  uint2 p;
  p.x = (uint32_t)f2bf(v.x) | ((uint32_t)f2bf(v.y) << 16);
  p.y = (uint32_t)f2bf(v.z) | ((uint32_t)f2bf(v.w) << 16);
  ((uint2*)out)[i] = p;
}

__global__ void cvt_w_kernel(const float4* __restrict__ w, const float4* __restrict__ m,
                             u16* __restrict__ out) {
  int i = blockIdx.x * 256 + threadIdx.x;
  float4 wv = w[i];
  float4 mv = m[i];
  uint2 p;
  p.x = (uint32_t)f2bf(wv.x * mv.x) | ((uint32_t)f2bf(wv.y * mv.y) << 16);
  p.y = (uint32_t)f2bf(wv.z * mv.z) | ((uint32_t)f2bf(wv.w * mv.w) << 16);
  ((uint2*)out)[i] = p;
}

// ---- async global->LDS 16B copy (m97 recipe) ----

__device__ __forceinline__ void async_cp16(const void* g, void* l) {
  __builtin_amdgcn_global_load_lds(
      (const __attribute__((address_space(1))) void*)g,
      (__attribute__((address_space(3))) void*)l,
      16, 0, 0);
}

// ---- bf16 MFMA GEMM: C[M][N] = A[M][K] * B[N][K]^T + bias ----
// 128x128 tile, BK=32, 256 threads = 4 waves (2x2), each wave 64x64 = 4x4 frags.

__global__ __launch_bounds__(256) void gemm_bf16(const u16* __restrict__ A,
                                                 const u16* __restrict__ B,
                                                 const float* __restrict__ bias,
                                                 float* __restrict__ C) {
  __shared__ u16 lsA[128 * 32];
  __shared__ u16 lsB[128 * 32];
  const int K = IN_F, N = OUT_F;
  const int tid = threadIdx.x;
  const int lane = tid & 63, wave = tid >> 6;
  const int waveM = (wave & 1) * 64, waveN = (wave >> 1) * 64;
  const long bm = (long)blockIdx.x * 128;
  const long bn = (long)blockIdx.y * 128;

  // staging: tile is [128 rows][64 bytes]; thread stages bytes [o1,o1+16) and [o2,o2+16)
  const int o1 = tid * 16;
  const int o2 = o1 + 4096;
  const u16* gA1 = A + (bm + (o1 >> 6)) * K + ((o1 & 63) >> 1);
  const u16* gA2 = A + (bm + (o2 >> 6)) * K + ((o2 & 63) >> 1);
  const u16* gB1 = B + (bn + (o1 >> 6)) * K + ((o1 & 63) >> 1);
  const u16* gB2 = B + (bn + (o2 >> 6)) * K + ((o2 & 63) >> 1);
  char* lA1 = (char*)lsA + o1;
  char* lA2 = (char*)lsA + o2;
  char* lB1 = (char*)lsB + o1;
  char* lB2 = (char*)lsB + o2;

  f32x4 acc[4][4];
#pragma unroll
  for (int i = 0; i < 4; i++)
#pragma unroll
    for (int j = 0; j < 4; j++)
#pragma unroll
      for (int r = 0; r < 4; r++) acc[i][j][r] = 0.0f;

  const int mrow = lane & 15;         // m (or n) within frag
  const int kq = (lane >> 4) * 8;     // k quad offset

  for (int k0 = 0; k0 < K; k0 += 32) {
    async_cp16(gA1 + k0, lA1);
    async_cp16(gA2 + k0, lA2);
    async_cp16(gB1 + k0, lB1);
    async_cp16(gB2 + k0, lB2);
    __syncthreads();   // drains vmcnt: staged data visible

    bf16x8 af[4], bfr[4];
#pragma unroll
    for (int i = 0; i < 4; i++)
      af[i] = *(const bf16x8*)&lsA[(waveM + i * 16 + mrow) * 32 + kq];
#pragma unroll
    for (int j = 0; j < 4; j++)
      bfr[j] = *(const bf16x8*)&lsB[(waveN + j * 16 + mrow) * 32 + kq];

#pragma unroll
    for (int i = 0; i < 4; i++)
#pragma unroll
      for (int j = 0; j < 4; j++)
        acc[i][j] = __builtin_amdgcn_mfma_f32_16x16x32_bf16(af[i], bfr[j], acc[i][j], 0, 0, 0);

    __syncthreads();   // all ds_reads done before next stage overwrites LDS
  }

  // epilogue: C/D layout col=lane&15, row=(lane>>4)*4+r  [m89-verified]
  const int cn = lane & 15;
  const int crow = (lane >> 4) * 4;
#pragma unroll
  for (int j = 0; j < 4; j++) {
    const long n = bn + waveN + j * 16 + cn;
    const float bv = bias[n];
#pragma unroll
    for (int i = 0; i < 4; i++) {
      const long m0 = bm + waveM + i * 16 + crow;
      float* cp = C + m0 * N + n;
#pragma unroll
      for (int r = 0; r < 4; r++)
        cp[(long)r * N] = acc[i][j][r] + bv;
    }
  }
}

// ---- fallback (only if d_ws is too small): exact fp32, slow but correct ----

__global__ void naive_kernel(const float* __restrict__ x, const float* __restrict__ w,
                             const float* __restrict__ bias, const float* __restrict__ m,
                             float* __restrict__ out) {
  size_t idx = (size_t)blockIdx.x * 256 + threadIdx.x;
  int o = (int)(idx % OUT_F);
  size_t b = idx / OUT_F;
  float s = bias[o];
  const float* xr = x + b * IN_F;
  const float* wr = w + (size_t)o * IN_F;
  const float* mr = m + (size_t)o * IN_F;
  for (int k = 0; k < IN_F; k++) s += xr[k] * wr[k] * mr[k];
  out[idx] = s;
}

extern "C" void kernel_launch(void* const* d_in, const int* in_sizes, int n_in,
                              void* d_out, int out_size, void* d_ws, size_t ws_size,
                              hipStream_t stream) {
  const float* x = (const float*)d_in[0];
  const float* w = (const float*)d_in[1];
  const float* bias = (const float*)d_in[2];
  const float* mask = (const float*)d_in[3];
  float* out = (float*)d_out;

  const size_t xb_elems = (size_t)BATCH * IN_F;       // 33.5M bf16 = 64 MB
  const size_t wm_elems = (size_t)OUT_F * IN_F;       // 4.2M bf16 = 8 MB
  const size_t need = (xb_elems + wm_elems) * sizeof(u16);

  if (ws_size >= need) {
    u16* xb = (u16*)d_ws;
    u16* wm = xb + xb_elems;
    cvt_x_kernel<<<(uint32_t)(xb_elems / 4 / 256), 256, 0, stream>>>((const float4*)x, xb);
    cvt_w_kernel<<<(uint32_t)(wm_elems / 4 / 256), 256, 0, stream>>>((const float4*)w,
                                                                     (const float4*)mask, wm);
    gemm_bf16<<<dim3(BATCH / 128, OUT_F / 128), 256, 0, stream>>>(xb, wm, bias, out);
  } else {
    naive_kernel<<<(uint32_t)(((size_t)BATCH * OUT_F) / 256), 256, 0, stream>>>(x, w, bias, mask, out);
  }
}

// Round 2
// 407.245 us; speedup vs baseline: 1.0147x; 1.0147x over previous
//
#include <hip/hip_runtime.h>
#include <stdint.h>

#define BATCH 16384
#define IN_F 2048
#define OUT_F 2048

typedef unsigned short u16;
typedef __attribute__((ext_vector_type(8))) short bf16x8;
typedef __attribute__((ext_vector_type(4))) float f32x4;

__device__ __forceinline__ u16 f2bf(float f) {
  union { float f; uint32_t u; } v; v.f = f;
  uint32_t u = v.u;
  u += 0x7FFFu + ((u >> 16) & 1u);   // round-to-nearest-even
  return (u16)(u >> 16);
}

// ---- prologue: fp32 -> bf16 conversion kernels ----

__global__ void cvt_x_kernel(const float4* __restrict__ x, u16* __restrict__ out) {
  int i = blockIdx.x * 256 + threadIdx.x;
  float4 v = x[i];
  uint2 p;
  p.x = (uint32_t)f2bf(v.x) | ((uint32_t)f2bf(v.y) << 16);
  p.y = (uint32_t)f2bf(v.z) | ((uint32_t)f2bf(v.w) << 16);
  ((uint2*)out)[i] = p;
}

__global__ void cvt_w_kernel(const float4* __restrict__ w, const float4* __restrict__ m,
                             u16* __restrict__ out) {
  int i = blockIdx.x * 256 + threadIdx.x;
  float4 wv = w[i];
  float4 mv = m[i];
  uint2 p;
  p.x = (uint32_t)f2bf(wv.x * mv.x) | ((uint32_t)f2bf(wv.y * mv.y) << 16);
  p.y = (uint32_t)f2bf(wv.z * mv.z) | ((uint32_t)f2bf(wv.w * mv.w) << 16);
  ((uint2*)out)[i] = p;
}

// ---- async global->LDS 16B copy (m97 recipe) ----

__device__ __forceinline__ void async_cp16(const void* g, void* l) {
  __builtin_amdgcn_global_load_lds(
      (const __attribute__((address_space(1))) void*)g,
      (__attribute__((address_space(3))) void*)l,
      16, 0, 0);
}

// ---- bf16 MFMA GEMM: C[M][N] = A[M][K] * B[N][K]^T + bias ----
// 128x128 tile, BK=32, 256 threads = 4 waves (2x2), each wave 64x64 = 4x4 frags.
// LDS tiles are [128 rows][4 x 16B chunks]; chunk index XOR-swizzled by
// s(r) = (r>>1)&3 so ds_read_b128 bank-quads are only 2-way aliased (free,
// m136) instead of 8-way (~2.9x). Staging compensates by loading global
// chunk c^s(r) into slot c (global_load_lds forces LDS slot = lane*16B).

__global__ __launch_bounds__(256) void gemm_bf16(const u16* __restrict__ A,
                                                 const u16* __restrict__ B,
                                                 const float* __restrict__ bias,
                                                 float* __restrict__ C) {
  __shared__ u16 lsA[128 * 32];
  __shared__ u16 lsB[128 * 32];
  const int K = IN_F, N = OUT_F;
  const int tid = threadIdx.x;
  const int lane = tid & 63, wave = tid >> 6;
  const int waveM = (wave & 1) * 64, waveN = (wave >> 1) * 64;
  const long bm = (long)blockIdx.x * 128;
  const long bn = (long)blockIdx.y * 128;

  // staging: thread tid stages rows r1=tid>>2 (A/B slot o1) and r2=r1+64.
  // slot chunk c = tid&3; swizzled source chunk cs = c ^ ((r>>1)&3).
  const int o1 = tid * 16;
  const int o2 = o1 + 4096;
  const int r1 = tid >> 2, r2 = r1 + 64;
  const int c = tid & 3;
  const int cs1 = c ^ ((r1 >> 1) & 3);
  const int cs2 = c ^ ((r2 >> 1) & 3);
  const u16* gA1 = A + (bm + r1) * K + cs1 * 8;
  const u16* gA2 = A + (bm + r2) * K + cs2 * 8;
  const u16* gB1 = B + (bn + r1) * K + cs1 * 8;
  const u16* gB2 = B + (bn + r2) * K + cs2 * 8;
  char* lA1 = (char*)lsA + o1;
  char* lA2 = (char*)lsA + o2;
  char* lB1 = (char*)lsB + o1;
  char* lB2 = (char*)lsB + o2;

  f32x4 acc[4][4];
#pragma unroll
  for (int i = 0; i < 4; i++)
#pragma unroll
    for (int j = 0; j < 4; j++)
#pragma unroll
      for (int r = 0; r < 4; r++) acc[i][j][r] = 0.0f;

  const int mrow = lane & 15;         // m (or n) within frag
  const int q = lane >> 4;            // k-quad index (16B chunks)

  for (int k0 = 0; k0 < K; k0 += 32) {
    async_cp16(gA1 + k0, lA1);
    async_cp16(gA2 + k0, lA2);
    async_cp16(gB1 + k0, lB1);
    async_cp16(gB2 + k0, lB2);
    __syncthreads();   // drains vmcnt: staged data visible

    bf16x8 af[4], bfr[4];
#pragma unroll
    for (int i = 0; i < 4; i++) {
      const int rr = waveM + i * 16 + mrow;
      af[i] = *(const bf16x8*)&lsA[rr * 32 + (q ^ ((rr >> 1) & 3)) * 8];
    }
#pragma unroll
    for (int j = 0; j < 4; j++) {
      const int rr = waveN + j * 16 + mrow;
      bfr[j] = *(const bf16x8*)&lsB[rr * 32 + (q ^ ((rr >> 1) & 3)) * 8];
    }

#pragma unroll
    for (int i = 0; i < 4; i++)
#pragma unroll
      for (int j = 0; j < 4; j++)
        acc[i][j] = __builtin_amdgcn_mfma_f32_16x16x32_bf16(af[i], bfr[j], acc[i][j], 0, 0, 0);

    __syncthreads();   // all ds_reads done before next stage overwrites LDS
  }

  // epilogue: C/D layout col=lane&15, row=(lane>>4)*4+r  [m89-verified]
  const int cn = lane & 15;
  const int crow = (lane >> 4) * 4;
#pragma unroll
  for (int j = 0; j < 4; j++) {
    const long n = bn + waveN + j * 16 + cn;
    const float bv = bias[n];
#pragma unroll
    for (int i = 0; i < 4; i++) {
      const long m0 = bm + waveM + i * 16 + crow;
      float* cp = C + m0 * N + n;
#pragma unroll
      for (int r = 0; r < 4; r++)
        cp[(long)r * N] = acc[i][j][r] + bv;
    }
  }
}

// ---- fallback (only if d_ws is too small): exact fp32, slow but correct ----

__global__ void naive_kernel(const float* __restrict__ x, const float* __restrict__ w,
                             const float* __restrict__ bias, const float* __restrict__ m,
                             float* __restrict__ out) {
  size_t idx = (size_t)blockIdx.x * 256 + threadIdx.x;
  int o = (int)(idx % OUT_F);
  size_t b = idx / OUT_F;
  float s = bias[o];
  const float* xr = x + b * IN_F;
  const float* wr = w + (size_t)o * IN_F;
  const float* mr = m + (size_t)o * IN_F;
  for (int k = 0; k < IN_F; k++) s += xr[k] * wr[k] * mr[k];
  out[idx] = s;
}

extern "C" void kernel_launch(void* const* d_in, const int* in_sizes, int n_in,
                              void* d_out, int out_size, void* d_ws, size_t ws_size,
                              hipStream_t stream) {
  const float* x = (const float*)d_in[0];
  const float* w = (const float*)d_in[1];
  const float* bias = (const float*)d_in[2];
  const float* mask = (const float*)d_in[3];
  float* out = (float*)d_out;

  const size_t xb_elems = (size_t)BATCH * IN_F;       // 33.5M bf16 = 64 MB
  const size_t wm_elems = (size_t)OUT_F * IN_F;       // 4.2M bf16 = 8 MB
  const size_t need = (xb_elems + wm_elems) * sizeof(u16);

  if (ws_size >= need) {
    u16* xb = (u16*)d_ws;
    u16* wm = xb + xb_elems;
    cvt_x_kernel<<<(uint32_t)(xb_elems / 4 / 256), 256, 0, stream>>>((const float4*)x, xb);
    cvt_w_kernel<<<(uint32_t)(wm_elems / 4 / 256), 256, 0, stream>>>((const float4*)w,
                                                                     (const float4*)mask, wm);
    gemm_bf16<<<dim3(BATCH / 128, OUT_F / 128), 256, 0, stream>>>(xb, wm, bias, out);
  } else {
    naive_kernel<<<(uint32_t)(((size_t)BATCH * OUT_F) / 256), 256, 0, stream>>>(x, w, bias, mask, out);
  }
}